// Round 4
// baseline (2690.741 us; speedup 1.0000x reference)
//
#include <hip/hip_runtime.h>
#include <math.h>

#define HH 480
#define WW 640
#define RAD 8
#define KK 17
#define DD 128
#define HWPIX (HH*WW)       // 307200
#define NBLK (HWPIX/256)    // 1200 exactly

static inline size_t al256(size_t x){ return (x + 255) & ~(size_t)255; }

// ---------- counting sort of events by pixel (row-major) ----------
__global__ void hist_kernel(const int* __restrict__ ey, const int* __restrict__ ex,
                            unsigned* __restrict__ off, int N) {
    int e = blockIdx.x*blockDim.x + threadIdx.x;
    if (e >= N) return;
    atomicAdd(&off[ey[e]*WW + ex[e]], 1u);
}

__global__ void scan1_kernel(unsigned* __restrict__ off, unsigned* __restrict__ bs) {
    __shared__ unsigned sh[256];
    int t = threadIdx.x, b = blockIdx.x;
    unsigned v = off[b*256 + t];
    sh[t] = v; __syncthreads();
    for (int st = 1; st < 256; st <<= 1) {
        unsigned a = (t >= st) ? sh[t-st] : 0u;
        __syncthreads();
        sh[t] += a;
        __syncthreads();
    }
    off[b*256 + t] = sh[t] - v;          // exclusive within block
    if (t == 255) bs[b] = sh[255];       // block total
}

__global__ void scan2_kernel(unsigned* __restrict__ bs) {
    __shared__ unsigned sh[256];
    __shared__ unsigned carry;
    int t = threadIdx.x;
    if (t == 0) carry = 0u;
    __syncthreads();
    for (int base = 0; base < NBLK; base += 256) {
        int i = base + t;
        unsigned v = (i < NBLK) ? bs[i] : 0u;
        sh[t] = v; __syncthreads();
        for (int st = 1; st < 256; st <<= 1) {
            unsigned a = (t >= st) ? sh[t-st] : 0u;
            __syncthreads();
            sh[t] += a;
            __syncthreads();
        }
        unsigned tot = sh[255];
        if (i < NBLK) bs[i] = (sh[t] - v) + carry;
        __syncthreads();
        if (t == 0) carry += tot;
        __syncthreads();
    }
}

__global__ void scan3_kernel(unsigned* __restrict__ off, const unsigned* __restrict__ bs) {
    int i = blockIdx.x*256 + threadIdx.x;
    off[i] += bs[blockIdx.x];
}

// leaves off[pix] = END of bucket; start = pix ? off[pix-1] : 0
__global__ void sort_kernel(const int* __restrict__ ey, const int* __restrict__ ex,
                            const float* __restrict__ t, unsigned* __restrict__ off,
                            float* __restrict__ tss, int* __restrict__ xs, int N) {
    int e = blockIdx.x*blockDim.x + threadIdx.x;
    if (e >= N) return;
    int pix = ey[e]*WW + ex[e];
    unsigned pos = atomicAdd(&off[pix], 1u);
    tss[pos] = t[e];
    xs[pos]  = ex[e];
}

// ---------- event-direct query: block = 2 queries x 128 dims ----------
__global__ __launch_bounds__(256) void query_kernel(
        const int* __restrict__ qy, const int* __restrict__ qx,
        const float* __restrict__ qt, const float* __restrict__ Tw,
        const float* __restrict__ Xw, const float* __restrict__ Yw,
        const unsigned* __restrict__ off, const float* __restrict__ tss,
        const int* __restrict__ xs, float* __restrict__ out,
        int M, long long out_n, int real_only) {
    __shared__ float2 swx[KK*DD];   // exp(i*(j-8)/8 * X[d])
    __shared__ float2 swy[KK*DD];   // exp(i*(i-8)/8 * Y[d])
    int lt = threadIdx.x;
    for (int idx = lt; idx < KK*DD; idx += 256) {
        int j = idx / DD, dd = idx & (DD-1);
        float s, c;
        sincosf((float)(j - RAD) * 0.125f * Xw[dd], &s, &c);
        swx[idx] = make_float2(c, s);
        sincosf((float)(j - RAD) * 0.125f * Yw[dd], &s, &c);
        swy[idx] = make_float2(c, s);
    }
    __syncthreads();

    int q = blockIdx.x*2 + (lt >> 7);
    int d = lt & (DD-1);
    if (q >= M) return;

    int cy = qy[q], cx = qx[q];
    float Td = Tw[d];
    int xlo = cx - RAD; if (xlo < 0) xlo = 0;
    int xhi = cx + RAD; if (xhi > WW-1) xhi = WW-1;

    float accr = 0.f, acci = 0.f;
    unsigned cnt = 0;

    for (int i = 0; i < KK; ++i) {
        int yy = cy + i - RAD;
        if ((unsigned)yy >= HH) continue;
        int plo = yy*WW + xlo, phi = yy*WW + xhi;
        unsigned st = plo ? off[plo-1] : 0u;   // contiguous event range of this row segment
        unsigned en = off[phi];
        cnt += en - st;
        float rr = 0.f, ri = 0.f;
        for (unsigned p = st; p < en; ++p) {   // wave-uniform loop (no divergence)
            float te = tss[p];
            int   xe = xs[p];
            float2 wx = swx[(xe - cx + RAD)*DD + d];
            float s, c;
            __sincosf(te * Td, &s, &c);        // exp(i t T_d)
            rr = fmaf(c, wx.x, rr); rr = fmaf(-s, wx.y, rr);
            ri = fmaf(c, wx.y, ri); ri = fmaf(s, wx.x, ri);
        }
        float2 wy = swy[i*DD + d];
        accr = fmaf(rr, wy.x, accr); accr = fmaf(-ri, wy.y, accr);
        acci = fmaf(rr, wy.y, acci); acci = fmaf(ri, wy.x, acci);
    }

    float s, c;
    sincosf(qt[q] * Td, &s, &c);               // recen = exp(-i qt T_d)
    float inv = 1.0f / fmaxf((float)cnt, 1.0f);
    float outr = (accr*c + acci*s) * inv;
    float outi = (acci*c - accr*s) * inv;
    long long base = (long long)q*DD + d;
    if (real_only) {
        if (base < out_n) out[base] = outr;
    } else {
        if (2*base + 1 < out_n) { out[2*base] = outr; out[2*base + 1] = outi; }
    }
}

extern "C" void kernel_launch(void* const* d_in, const int* in_sizes, int n_in,
                              void* d_out, int out_size, void* d_ws, size_t ws_size,
                              hipStream_t stream) {
    const float* t  = (const float*)d_in[0];
    const int*   ey = (const int*)d_in[1];
    const int*   ex = (const int*)d_in[2];
    const int*   qy = (const int*)d_in[3];
    const int*   qx = (const int*)d_in[4];
    const float* qt = (const float*)d_in[5];
    const float* Tw = (const float*)d_in[6];
    const float* Xw = (const float*)d_in[7];
    const float* Yw = (const float*)d_in[8];

    int N = in_sizes[0];
    int M = in_sizes[3];

    // ws layout: [off u32[HWPIX] | bs u32[NBLK] | tss f32[N] | xs i32[N]]
    size_t off_b = al256((size_t)HWPIX*4);
    size_t bs_b  = al256((size_t)NBLK*4);
    size_t tss_b = al256((size_t)N*4);
    size_t xs_b  = al256((size_t)N*4);
    size_t need  = off_b + bs_b + tss_b + xs_b;   // ~5.3 MB

    if (ws_size < need || d_ws == nullptr) {
        // diagnostic fallback: no scratch available -> safe zero output (absmax-fails, never faults)
        hipMemsetAsync(d_out, 0, (size_t)out_size*4, stream);
        return;
    }

    unsigned* off = (unsigned*)d_ws;
    unsigned* bs  = (unsigned*)((char*)d_ws + off_b);
    float*    tss = (float*)((char*)d_ws + off_b + bs_b);
    int*      xs  = (int*)((char*)d_ws + off_b + bs_b + tss_b);

    // output contract: complex64 likely stored as real-part float32 (out_size == M*D);
    // if out_size >= 2*M*D, it's interleaved re/im instead. Decide at runtime.
    long long full = (long long)M * DD;
    int real_only = (out_size < 2*full) ? 1 : 0;

    hipMemsetAsync(off, 0, (size_t)HWPIX*4, stream);
    hist_kernel<<<(N+255)/256, 256, 0, stream>>>(ey, ex, off, N);
    scan1_kernel<<<NBLK, 256, 0, stream>>>(off, bs);
    scan2_kernel<<<1, 256, 0, stream>>>(bs);
    scan3_kernel<<<NBLK, 256, 0, stream>>>(off, bs);
    sort_kernel<<<(N+255)/256, 256, 0, stream>>>(ey, ex, t, off, tss, xs, N);

    query_kernel<<<(M+1)/2, 256, 0, stream>>>(qy, qx, qt, Tw, Xw, Yw,
                                              off, tss, xs, (float*)d_out,
                                              M, (long long)out_size, real_only);
}

// Round 5
// 2676.998 us; speedup vs baseline: 1.0051x; 1.0051x over previous
//
#include <hip/hip_runtime.h>
#include <math.h>

#define HH 480
#define WW 640
#define RAD 8
#define KK 17
#define W2 (WW + 2*RAD)      // 656, x-padded row width
#define DD 128
#define HWPIX (HH*WW)        // 307200
#define NBLK (HWPIX/256)     // 1200 exactly

static inline size_t al256(size_t x){ return (x + 255) & ~(size_t)255; }

// ================= counting sort of events by pixel (validated in v4) =================
__global__ void hist_kernel(const int* __restrict__ ey, const int* __restrict__ ex,
                            unsigned* __restrict__ off, int N) {
    int e = blockIdx.x*blockDim.x + threadIdx.x;
    if (e >= N) return;
    atomicAdd(&off[ey[e]*WW + ex[e]], 1u);
}

__global__ void scan1_kernel(unsigned* __restrict__ off, unsigned* __restrict__ bs) {
    __shared__ unsigned sh[256];
    int t = threadIdx.x, b = blockIdx.x;
    unsigned v = off[b*256 + t];
    sh[t] = v; __syncthreads();
    for (int st = 1; st < 256; st <<= 1) {
        unsigned a = (t >= st) ? sh[t-st] : 0u;
        __syncthreads();
        sh[t] += a;
        __syncthreads();
    }
    off[b*256 + t] = sh[t] - v;
    if (t == 255) bs[b] = sh[255];
}

__global__ void scan2_kernel(unsigned* __restrict__ bs) {
    __shared__ unsigned sh[256];
    __shared__ unsigned carry;
    int t = threadIdx.x;
    if (t == 0) carry = 0u;
    __syncthreads();
    for (int base = 0; base < NBLK; base += 256) {
        int i = base + t;
        unsigned v = (i < NBLK) ? bs[i] : 0u;
        sh[t] = v; __syncthreads();
        for (int st = 1; st < 256; st <<= 1) {
            unsigned a = (t >= st) ? sh[t-st] : 0u;
            __syncthreads();
            sh[t] += a;
            __syncthreads();
        }
        unsigned tot = sh[255];
        if (i < NBLK) bs[i] = (sh[t] - v) + carry;
        __syncthreads();
        if (t == 0) carry += tot;
        __syncthreads();
    }
}

__global__ void scan3_kernel(unsigned* __restrict__ off, const unsigned* __restrict__ bs) {
    int i = blockIdx.x*256 + threadIdx.x;
    off[i] += bs[blockIdx.x];
}

// leaves off[pix] = END of bucket; start = pix ? off[pix-1] : 0
__global__ void sort_kernel(const int* __restrict__ ey, const int* __restrict__ ex,
                            const float* __restrict__ t, unsigned* __restrict__ off,
                            float* __restrict__ tss, int* __restrict__ xs, int N) {
    int e = blockIdx.x*blockDim.x + threadIdx.x;
    if (e >= N) return;
    int pix = ey[e]*WW + ex[e];
    unsigned pos = atomicAdd(&off[pix], 1u);
    tss[pos] = t[e];
    xs[pos]  = ex[e];
}

// ---------- per-query window event count (telescoping row ranges) ----------
__global__ void qcnt_kernel(const int* __restrict__ qy, const int* __restrict__ qx,
                            const unsigned* __restrict__ off, float* __restrict__ qcnt, int M) {
    int q = blockIdx.x*blockDim.x + threadIdx.x;
    if (q >= M) return;
    int cy = qy[q], cx = qx[q];
    int xlo = cx - RAD; if (xlo < 0) xlo = 0;
    int xhi = cx + RAD; if (xhi > WW-1) xhi = WW-1;
    unsigned s = 0;
    for (int i = 0; i < KK; ++i) {
        int yy = cy + i - RAD;
        if ((unsigned)yy >= HH) continue;
        int plo = yy*WW + xlo, phi = yy*WW + xhi;
        unsigned st = plo ? off[plo-1] : 0u;
        s += off[phi] - st;
    }
    qcnt[q] = (float)s;
}

// ================= dense band grid path =================
// build: one thread per (padded cell, d); serially sums exp(i t T_d) of its <=~few events
template<int DC>
__global__ __launch_bounds__(256) void build_kernel(
        const unsigned* __restrict__ off, const float* __restrict__ tss,
        const float* __restrict__ Tw, float2* __restrict__ grid,
        int r0, int rows, int dlo) {
    long long gid = (long long)blockIdx.x*256 + threadIdx.x;
    long long total = (long long)rows * W2 * DC;
    if (gid >= total) return;
    int dd = (int)(gid & (DC-1));
    long long cell = gid / DC;
    int lx   = (int)(cell % W2);
    int lrow = (int)(cell / W2);
    int gx = lx - RAD;
    int gy = r0 - RAD + lrow;
    float sr = 0.f, si = 0.f;
    if ((unsigned)gx < WW && (unsigned)gy < HH) {
        int pix = gy*WW + gx;
        unsigned st = pix ? off[pix-1] : 0u;
        unsigned en = off[pix];
        float Td = Tw[dlo + dd];
        for (unsigned p = st; p < en; ++p) {
            float s, c;
            __sincosf(tss[p] * Td, &s, &c);
            sr += c; si += s;
        }
    }
    grid[cell*DC + dd] = make_float2(sr, si);
}

// query: separable 17x17 gather, weights in registers via rotation recurrences
template<int DC>
__global__ __launch_bounds__(256) void query_conv_kernel(
        const int* __restrict__ qy, const int* __restrict__ qx,
        const float* __restrict__ qt, const float* __restrict__ Tw,
        const float* __restrict__ Xw, const float* __restrict__ Yw,
        const float2* __restrict__ grid, const float* __restrict__ qcnt,
        float* __restrict__ out, int M, int r0, int band, int dlo,
        long long out_n, int real_only) {
    int lt = threadIdx.x;
    int q  = blockIdx.x*(256/DC) + lt/DC;
    int dd = lt & (DC-1);
    if (q >= M) return;
    int cy = qy[q];
    if (cy < r0 || cy >= r0 + band) return;   // this band owns cy in [r0, r0+band)
    int cx = qx[q];
    int d  = dlo + dd;

    // wx[j] = exp(i*(j-8)/8 * X[d]) by rotation; conj symmetry for j<8
    float xr[KK], xi[KK];
    {
        float s, c;
        sincosf(Xw[d] * 0.125f, &s, &c);
        xr[RAD] = 1.f; xi[RAD] = 0.f;
        #pragma unroll
        for (int m = 1; m <= RAD; ++m) {
            xr[RAD+m] = xr[RAD+m-1]*c - xi[RAD+m-1]*s;
            xi[RAD+m] = xr[RAD+m-1]*s + xi[RAD+m-1]*c;
            xr[RAD-m] =  xr[RAD+m];
            xi[RAD-m] = -xi[RAD+m];
        }
    }
    // wy walks i=0..16: start exp(-i*Y[d]), step exp(+i*Y[d]/8)
    float wyr, wyi, cst, sst;
    {
        float s, c, Yd = Yw[d];
        sincosf(-Yd, &s, &c);        wyr = c; wyi = s;
        sincosf(Yd * 0.125f, &sst, &cst);
    }

    int lrow0 = cy - r0;   // local row of window top (pad shifts cancel)
    float er = 0.f, ei = 0.f;
    for (int i = 0; i < KK; ++i) {
        const float2* gp = grid + ((long long)(lrow0 + i)*W2 + cx)*DC + dd;
        float rr = 0.f, ri = 0.f;
        #pragma unroll
        for (int j = 0; j < KK; ++j) {
            float2 f = gp[j*DC];
            rr = fmaf(f.x, xr[j], rr); rr = fmaf(-f.y, xi[j], rr);
            ri = fmaf(f.x, xi[j], ri); ri = fmaf(f.y, xr[j], ri);
        }
        er = fmaf(rr, wyr, er); er = fmaf(-ri, wyi, er);
        ei = fmaf(rr, wyi, ei); ei = fmaf(ri, wyr, ei);
        float nr = wyr*cst - wyi*sst;
        wyi      = wyr*sst + wyi*cst;
        wyr      = nr;
    }

    float s, c;
    sincosf(qt[q] * Tw[d], &s, &c);          // recen = exp(-i qt T_d)
    float inv = 1.0f / fmaxf(qcnt[q], 1.0f);
    float outr = (er*c + ei*s) * inv;
    float outi = (ei*c - er*s) * inv;
    long long base = (long long)q*DD + d;
    if (real_only) { if (base < out_n) out[base] = outr; }
    else if (2*base + 1 < out_n) { out[2*base] = outr; out[2*base+1] = outi; }
}

// ================= fallback: event-direct query (validated v4, 2.69 ms) =================
__global__ __launch_bounds__(256) void query_direct_kernel(
        const int* __restrict__ qy, const int* __restrict__ qx,
        const float* __restrict__ qt, const float* __restrict__ Tw,
        const float* __restrict__ Xw, const float* __restrict__ Yw,
        const unsigned* __restrict__ off, const float* __restrict__ tss,
        const int* __restrict__ xs, float* __restrict__ out,
        int M, long long out_n, int real_only) {
    __shared__ float2 swx[KK*DD];
    __shared__ float2 swy[KK*DD];
    int lt = threadIdx.x;
    for (int idx = lt; idx < KK*DD; idx += 256) {
        int j = idx / DD, dd = idx & (DD-1);
        float s, c;
        sincosf((float)(j - RAD) * 0.125f * Xw[dd], &s, &c);
        swx[idx] = make_float2(c, s);
        sincosf((float)(j - RAD) * 0.125f * Yw[dd], &s, &c);
        swy[idx] = make_float2(c, s);
    }
    __syncthreads();

    int q = blockIdx.x*2 + (lt >> 7);
    int d = lt & (DD-1);
    if (q >= M) return;

    int cy = qy[q], cx = qx[q];
    float Td = Tw[d];
    int xlo = cx - RAD; if (xlo < 0) xlo = 0;
    int xhi = cx + RAD; if (xhi > WW-1) xhi = WW-1;

    float accr = 0.f, acci = 0.f;
    unsigned cnt = 0;
    for (int i = 0; i < KK; ++i) {
        int yy = cy + i - RAD;
        if ((unsigned)yy >= HH) continue;
        int plo = yy*WW + xlo, phi = yy*WW + xhi;
        unsigned st = plo ? off[plo-1] : 0u;
        unsigned en = off[phi];
        cnt += en - st;
        float rr = 0.f, ri = 0.f;
        for (unsigned p = st; p < en; ++p) {
            float te = tss[p];
            int   xe = xs[p];
            float2 wx = swx[(xe - cx + RAD)*DD + d];
            float s, c;
            __sincosf(te * Td, &s, &c);
            rr = fmaf(c, wx.x, rr); rr = fmaf(-s, wx.y, rr);
            ri = fmaf(c, wx.y, ri); ri = fmaf(s, wx.x, ri);
        }
        float2 wy = swy[i*DD + d];
        accr = fmaf(rr, wy.x, accr); accr = fmaf(-ri, wy.y, accr);
        acci = fmaf(rr, wy.y, acci); acci = fmaf(ri, wy.x, acci);
    }

    float s, c;
    sincosf(qt[q] * Td, &s, &c);
    float inv = 1.0f / fmaxf((float)cnt, 1.0f);
    float outr = (accr*c + acci*s) * inv;
    float outi = (acci*c - accr*s) * inv;
    long long base = (long long)q*DD + d;
    if (real_only) { if (base < out_n) out[base] = outr; }
    else if (2*base + 1 < out_n) { out[2*base] = outr; out[2*base+1] = outi; }
}

extern "C" void kernel_launch(void* const* d_in, const int* in_sizes, int n_in,
                              void* d_out, int out_size, void* d_ws, size_t ws_size,
                              hipStream_t stream) {
    const float* t  = (const float*)d_in[0];
    const int*   ey = (const int*)d_in[1];
    const int*   ex = (const int*)d_in[2];
    const int*   qy = (const int*)d_in[3];
    const int*   qx = (const int*)d_in[4];
    const float* qt = (const float*)d_in[5];
    const float* Tw = (const float*)d_in[6];
    const float* Xw = (const float*)d_in[7];
    const float* Yw = (const float*)d_in[8];

    int N = in_sizes[0];
    int M = in_sizes[3];

    // ws: [off u32[HWPIX] | bs u32[NBLK] | tss f32[N] | xs i32[N] | qcnt f32[M] | grid...]
    size_t off_b = al256((size_t)HWPIX*4);
    size_t bs_b  = al256((size_t)NBLK*4);
    size_t tss_b = al256((size_t)N*4);
    size_t xs_b  = al256((size_t)N*4);
    size_t qc_b  = al256((size_t)M*4);
    size_t fixed = off_b + bs_b + tss_b + xs_b + qc_b;   // ~5.6 MB

    if (ws_size < fixed - qc_b || d_ws == nullptr) {
        hipMemsetAsync(d_out, 0, (size_t)out_size*4, stream);   // safe diagnostic
        return;
    }

    unsigned* off  = (unsigned*)d_ws;
    unsigned* bs   = (unsigned*)((char*)d_ws + off_b);
    float*    tss  = (float*)((char*)d_ws + off_b + bs_b);
    int*      xs   = (int*)((char*)d_ws + off_b + bs_b + tss_b);
    float*    qcnt = (float*)((char*)d_ws + off_b + bs_b + tss_b + xs_b);
    float2*   grid = (float2*)((char*)d_ws + fixed);

    long long full = (long long)M * DD;
    int real_only = (out_size < 2*full) ? 1 : 0;

    hipMemsetAsync(off, 0, (size_t)HWPIX*4, stream);
    hist_kernel<<<(N+255)/256, 256, 0, stream>>>(ey, ex, off, N);
    scan1_kernel<<<NBLK, 256, 0, stream>>>(off, bs);
    scan2_kernel<<<1, 256, 0, stream>>>(bs);
    scan3_kernel<<<NBLK, 256, 0, stream>>>(off, bs);
    sort_kernel<<<(N+255)/256, 256, 0, stream>>>(ey, ex, t, off, tss, xs, N);

    // choose dense-grid config: need band>=32 rows; cap grid at ~64MB (L3-resident)
    int DC = 0, BAND = 0;
    if (ws_size > fixed) {
        size_t rem = ws_size - fixed;
        for (int dc = 128; dc >= 8; dc >>= 1) {
            size_t rowb = (size_t)W2 * dc * 8;
            long long rows = (long long)(rem / rowb);
            long long cap  = (long long)((size_t)(64u<<20) / rowb) - 16;
            long long band = rows - 16;
            if (band > cap) band = cap;
            if (band > HH)  band = HH;
            if (band >= 32) { DC = dc; BAND = (int)band; break; }
        }
    }

    if (DC == 0) {
        // event-direct fallback (validated): no qcnt/grid needed
        query_direct_kernel<<<(M+1)/2, 256, 0, stream>>>(
            qy, qx, qt, Tw, Xw, Yw, off, tss, xs, (float*)d_out,
            M, (long long)out_size, real_only);
        return;
    }

    qcnt_kernel<<<(M+255)/256, 256, 0, stream>>>(qy, qx, off, qcnt, M);

#define PASS(DCV)                                                                           \
    {                                                                                       \
        long long btot = (long long)rows * W2 * DCV;                                        \
        build_kernel<DCV><<<(int)((btot+255)/256), 256, 0, stream>>>(                       \
            off, tss, Tw, grid, r0, rows, dlo);                                             \
        int qpb = 256 / DCV;                                                                \
        query_conv_kernel<DCV><<<(M+qpb-1)/qpb, 256, 0, stream>>>(                          \
            qy, qx, qt, Tw, Xw, Yw, grid, qcnt, (float*)d_out,                              \
            M, r0, band, dlo, (long long)out_size, real_only);                              \
    }

    for (int dlo = 0; dlo < DD; dlo += DC) {
        for (int r0 = 0; r0 < HH; r0 += BAND) {
            int band = HH - r0 < BAND ? HH - r0 : BAND;
            int rows = band + 16;
            switch (DC) {
                case 128: PASS(128); break;
                case 64:  PASS(64);  break;
                case 32:  PASS(32);  break;
                case 16:  PASS(16);  break;
                default:  PASS(8);   break;
            }
        }
    }
#undef PASS
}

// Round 6
// 908.803 us; speedup vs baseline: 2.9608x; 2.9456x over previous
//
#include <hip/hip_runtime.h>
#include <math.h>

#define HH 480
#define WW 640
#define RAD 8
#define KK 17
#define W2 (WW + 2*RAD)      // 656, x-padded G row width
#define DD 128
#define HWPIX (HH*WW)        // 307200
#define NBLK (HWPIX/256)     // 1200 exactly

static inline size_t al256(size_t x){ return (x + 255) & ~(size_t)255; }

// ================= counting sort by pixel (validated v4/v5); reused for queries =================
__global__ void hist_kernel(const int* __restrict__ cy, const int* __restrict__ cx,
                            unsigned* __restrict__ off, int N) {
    int e = blockIdx.x*blockDim.x + threadIdx.x;
    if (e >= N) return;
    atomicAdd(&off[cy[e]*WW + cx[e]], 1u);
}

__global__ void scan1_kernel(unsigned* __restrict__ off, unsigned* __restrict__ bs) {
    __shared__ unsigned sh[256];
    int t = threadIdx.x, b = blockIdx.x;
    unsigned v = off[b*256 + t];
    sh[t] = v; __syncthreads();
    for (int st = 1; st < 256; st <<= 1) {
        unsigned a = (t >= st) ? sh[t-st] : 0u;
        __syncthreads();
        sh[t] += a;
        __syncthreads();
    }
    off[b*256 + t] = sh[t] - v;
    if (t == 255) bs[b] = sh[255];
}

__global__ void scan2_kernel(unsigned* __restrict__ bs) {
    __shared__ unsigned sh[256];
    __shared__ unsigned carry;
    int t = threadIdx.x;
    if (t == 0) carry = 0u;
    __syncthreads();
    for (int base = 0; base < NBLK; base += 256) {
        int i = base + t;
        unsigned v = (i < NBLK) ? bs[i] : 0u;
        sh[t] = v; __syncthreads();
        for (int st = 1; st < 256; st <<= 1) {
            unsigned a = (t >= st) ? sh[t-st] : 0u;
            __syncthreads();
            sh[t] += a;
            __syncthreads();
        }
        unsigned tot = sh[255];
        if (i < NBLK) bs[i] = (sh[t] - v) + carry;
        __syncthreads();
        if (t == 0) carry += tot;
        __syncthreads();
    }
}

__global__ void scan3_kernel(unsigned* __restrict__ off, const unsigned* __restrict__ bs) {
    int i = blockIdx.x*256 + threadIdx.x;
    off[i] += bs[blockIdx.x];
}

// leaves off[pix] = END of bucket; start = pix ? off[pix-1] : 0
__global__ void sort_kernel(const int* __restrict__ ey, const int* __restrict__ ex,
                            const float* __restrict__ t, unsigned* __restrict__ off,
                            float* __restrict__ tss, int* __restrict__ xs, int N) {
    int e = blockIdx.x*blockDim.x + threadIdx.x;
    if (e >= N) return;
    int pix = ey[e]*WW + ex[e];
    unsigned pos = atomicAdd(&off[pix], 1u);
    tss[pos] = t[e];
    xs[pos]  = ex[e];
}

__global__ void qsort_kernel(const int* __restrict__ qy, const int* __restrict__ qx,
                             unsigned* __restrict__ qoff, unsigned* __restrict__ qidx, int M) {
    int q = blockIdx.x*blockDim.x + threadIdx.x;
    if (q >= M) return;
    int pix = qy[q]*WW + qx[q];
    unsigned pos = atomicAdd(&qoff[pix], 1u);
    qidx[pos] = q;
}

// ---------- per-query window event count (telescoping row ranges; validated) ----------
__global__ void qcnt_kernel(const int* __restrict__ qy, const int* __restrict__ qx,
                            const unsigned* __restrict__ off, float* __restrict__ qcnt, int M) {
    int q = blockIdx.x*blockDim.x + threadIdx.x;
    if (q >= M) return;
    int cy = qy[q], cx = qx[q];
    int xlo = cx - RAD; if (xlo < 0) xlo = 0;
    int xhi = cx + RAD; if (xhi > WW-1) xhi = WW-1;
    unsigned s = 0;
    for (int i = 0; i < KK; ++i) {
        int yy = cy + i - RAD;
        if ((unsigned)yy >= HH) continue;
        int plo = yy*WW + xlo, phi = yy*WW + xhi;
        unsigned st = plo ? off[plo-1] : 0u;
        s += off[phi] - st;
    }
    qcnt[q] = (float)s;
}

// ================= G build: rows cover image rows [r0-8, r0-8+rows), x-padded =================
template<int DC>
__global__ __launch_bounds__(256) void build_kernel(
        const unsigned* __restrict__ off, const float* __restrict__ tss,
        const float* __restrict__ Tw, float2* __restrict__ grid,
        int r0, int rows, int dlo) {
    long long gid = (long long)blockIdx.x*256 + threadIdx.x;
    long long total = (long long)rows * W2 * DC;
    if (gid >= total) return;
    int dd = (int)(gid & (DC-1));
    long long cell = gid / DC;
    int lx   = (int)(cell % W2);
    int lrow = (int)(cell / W2);
    int gx = lx - RAD;
    int gy = r0 - RAD + lrow;
    float sr = 0.f, si = 0.f;
    if ((unsigned)gx < WW && (unsigned)gy < HH) {
        int pix = gy*WW + gx;
        unsigned st = pix ? off[pix-1] : 0u;
        unsigned en = off[pix];
        float Td = Tw[dlo + dd];
        for (unsigned p = st; p < en; ++p) {
            float s, c;
            __sincosf(tss[p] * Td, &s, &c);
            sr += c; si += s;
        }
    }
    grid[cell*DC + dd] = make_float2(sr, si);
}

// ================= horizontal conv: H[r][x][d] = sum_j wx_j G[r][x+j][d] =================
template<int DC>
__global__ __launch_bounds__(256) void convh_kernel(
        const float2* __restrict__ G, const float* __restrict__ Xw,
        float2* __restrict__ Hout, int rows, int dlo) {
    __shared__ float2 swx[KK*DC];
    int lt = threadIdx.x;
    for (int idx = lt; idx < KK*DC; idx += 256) {
        int j = idx / DC, dd = idx - j*DC;
        float s, c;
        sincosf((float)(j - RAD) * 0.125f * Xw[dlo + dd], &s, &c);
        swx[idx] = make_float2(c, s);
    }
    __syncthreads();
    long long gid = (long long)blockIdx.x*256 + lt;
    long long total = (long long)rows * WW * DC;
    if (gid >= total) return;
    int dd = (int)(gid & (DC-1));
    long long cell = gid / DC;           // = r*WW + x
    int x = (int)(cell % WW);
    int r = (int)(cell / WW);
    const float2* gp = G + ((long long)r*W2 + x)*DC + dd;   // padded col x+j = image col x+j-8
    float hr = 0.f, hi = 0.f;
    #pragma unroll
    for (int j = 0; j < KK; ++j) {
        float2 f = gp[j*DC];
        float2 w = swx[j*DC + dd];
        hr = fmaf(f.x, w.x, hr); hr = fmaf(-f.y, w.y, hr);
        hi = fmaf(f.x, w.y, hi); hi = fmaf(f.y, w.x, hi);
    }
    Hout[gid] = make_float2(hr, hi);     // H layout [r][x][dd] == linear gid
}

// ================= stage 2: 17-tap vertical gather on H, sorted queries =================
template<int DC>
__global__ __launch_bounds__(256) void query_sep_kernel(
        const unsigned* __restrict__ qidx, const int* __restrict__ qy,
        const int* __restrict__ qx, const float* __restrict__ qt,
        const float* __restrict__ Tw, const float* __restrict__ Yw,
        const float2* __restrict__ H, const float* __restrict__ qcnt,
        float* __restrict__ out, int M, int r0, int band, int rb0,
        int dlo, long long out_n, int real_only) {
    int lt = threadIdx.x;
    int p  = blockIdx.x*(256/DC) + lt/DC;
    int dd = lt & (DC-1);
    if (p >= M) return;
    int q = (int)qidx[p];
    int cy = qy[q];
    if (cy < r0 || cy >= r0 + band) return;
    int cx = qx[q];
    int d  = dlo + dd;

    // wy walks i=0..16: start exp(-i*Y[d]), step exp(+i*Y[d]/8)  (validated v5 math)
    float wyr, wyi, cst, sst;
    {
        float s, c, Yd = Yw[d];
        sincosf(-Yd, &s, &c);        wyr = c; wyi = s;
        sincosf(Yd * 0.125f, &sst, &cst);
    }

    const float2* hp = H + ((long long)(cy - 8 - rb0)*WW + cx)*DC + dd;
    float er = 0.f, ei = 0.f;
    #pragma unroll
    for (int i = 0; i < KK; ++i) {
        float2 f = hp[(long long)i*WW*DC];
        er = fmaf(f.x, wyr, er); er = fmaf(-f.y, wyi, er);
        ei = fmaf(f.x, wyi, ei); ei = fmaf(f.y, wyr, ei);
        float nr = wyr*cst - wyi*sst;
        wyi      = wyr*sst + wyi*cst;
        wyr      = nr;
    }

    float s, c;
    sincosf(qt[q] * Tw[d], &s, &c);          // recen = exp(-i qt T_d)
    float inv = 1.0f / fmaxf(qcnt[q], 1.0f);
    float outr = (er*c + ei*s) * inv;
    float outi = (ei*c - er*s) * inv;
    long long base = (long long)q*DD + d;
    if (real_only) { if (base < out_n) out[base] = outr; }
    else if (2*base + 1 < out_n) { out[2*base] = outr; out[2*base+1] = outi; }
}

// ================= fallback: event-direct query (validated v4, 2.69 ms) =================
__global__ __launch_bounds__(256) void query_direct_kernel(
        const int* __restrict__ qy, const int* __restrict__ qx,
        const float* __restrict__ qt, const float* __restrict__ Tw,
        const float* __restrict__ Xw, const float* __restrict__ Yw,
        const unsigned* __restrict__ off, const float* __restrict__ tss,
        const int* __restrict__ xs, float* __restrict__ out,
        int M, long long out_n, int real_only) {
    __shared__ float2 swx[KK*DD];
    __shared__ float2 swy[KK*DD];
    int lt = threadIdx.x;
    for (int idx = lt; idx < KK*DD; idx += 256) {
        int j = idx / DD, dd = idx & (DD-1);
        float s, c;
        sincosf((float)(j - RAD) * 0.125f * Xw[dd], &s, &c);
        swx[idx] = make_float2(c, s);
        sincosf((float)(j - RAD) * 0.125f * Yw[dd], &s, &c);
        swy[idx] = make_float2(c, s);
    }
    __syncthreads();

    int q = blockIdx.x*2 + (lt >> 7);
    int d = lt & (DD-1);
    if (q >= M) return;

    int cy = qy[q], cx = qx[q];
    float Td = Tw[d];
    int xlo = cx - RAD; if (xlo < 0) xlo = 0;
    int xhi = cx + RAD; if (xhi > WW-1) xhi = WW-1;

    float accr = 0.f, acci = 0.f;
    unsigned cnt = 0;
    for (int i = 0; i < KK; ++i) {
        int yy = cy + i - RAD;
        if ((unsigned)yy >= HH) continue;
        int plo = yy*WW + xlo, phi = yy*WW + xhi;
        unsigned st = plo ? off[plo-1] : 0u;
        unsigned en = off[phi];
        cnt += en - st;
        float rr = 0.f, ri = 0.f;
        for (unsigned p = st; p < en; ++p) {
            float te = tss[p];
            int   xe = xs[p];
            float2 wx = swx[(xe - cx + RAD)*DD + d];
            float s, c;
            __sincosf(te * Td, &s, &c);
            rr = fmaf(c, wx.x, rr); rr = fmaf(-s, wx.y, rr);
            ri = fmaf(c, wx.y, ri); ri = fmaf(s, wx.x, ri);
        }
        float2 wy = swy[i*DD + d];
        accr = fmaf(rr, wy.x, accr); accr = fmaf(-ri, wy.y, accr);
        acci = fmaf(rr, wy.y, acci); acci = fmaf(ri, wy.x, acci);
    }

    float s, c;
    sincosf(qt[q] * Td, &s, &c);
    float inv = 1.0f / fmaxf((float)cnt, 1.0f);
    float outr = (accr*c + acci*s) * inv;
    float outi = (acci*c - accr*s) * inv;
    long long base = (long long)q*DD + d;
    if (real_only) { if (base < out_n) out[base] = outr; }
    else if (2*base + 1 < out_n) { out[2*base] = outr; out[2*base+1] = outi; }
}

extern "C" void kernel_launch(void* const* d_in, const int* in_sizes, int n_in,
                              void* d_out, int out_size, void* d_ws, size_t ws_size,
                              hipStream_t stream) {
    const float* t  = (const float*)d_in[0];
    const int*   ey = (const int*)d_in[1];
    const int*   ex = (const int*)d_in[2];
    const int*   qy = (const int*)d_in[3];
    const int*   qx = (const int*)d_in[4];
    const float* qt = (const float*)d_in[5];
    const float* Tw = (const float*)d_in[6];
    const float* Xw = (const float*)d_in[7];
    const float* Yw = (const float*)d_in[8];

    int N = in_sizes[0];
    int M = in_sizes[3];

    // ws: [off | bs | tss | xs | qoff | qidx | qcnt | G/H buffers]
    size_t off_b  = al256((size_t)HWPIX*4);
    size_t bs_b   = al256((size_t)NBLK*4);
    size_t tss_b  = al256((size_t)N*4);
    size_t xs_b   = al256((size_t)N*4);
    size_t qoff_b = al256((size_t)HWPIX*4);
    size_t qidx_b = al256((size_t)M*4);
    size_t qc_b   = al256((size_t)M*4);
    size_t fixed  = off_b + bs_b + tss_b + xs_b + qoff_b + qidx_b + qc_b;  // ~8.5 MB
    size_t need_min = off_b + bs_b + tss_b + xs_b;                          // ~5.3 MB

    if (ws_size < need_min || d_ws == nullptr) {
        hipMemsetAsync(d_out, 0, (size_t)out_size*4, stream);   // safe diagnostic
        return;
    }

    char*     ws   = (char*)d_ws;
    unsigned* off  = (unsigned*)ws;
    unsigned* bs   = (unsigned*)(ws + off_b);
    float*    tss  = (float*)(ws + off_b + bs_b);
    int*      xs   = (int*)(ws + off_b + bs_b + tss_b);
    unsigned* qoff = (unsigned*)(ws + off_b + bs_b + tss_b + xs_b);
    unsigned* qidx = (unsigned*)(ws + off_b + bs_b + tss_b + xs_b + qoff_b);
    float*    qcnt = (float*)(ws + off_b + bs_b + tss_b + xs_b + qoff_b + qidx_b);

    long long full = (long long)M * DD;
    int real_only = (out_size < 2*full) ? 1 : 0;

    // ---- event sort (validated) ----
    hipMemsetAsync(off, 0, (size_t)HWPIX*4, stream);
    hist_kernel<<<(N+255)/256, 256, 0, stream>>>(ey, ex, off, N);
    scan1_kernel<<<NBLK, 256, 0, stream>>>(off, bs);
    scan2_kernel<<<1, 256, 0, stream>>>(bs);
    scan3_kernel<<<NBLK, 256, 0, stream>>>(off, bs);
    sort_kernel<<<(N+255)/256, 256, 0, stream>>>(ey, ex, t, off, tss, xs, N);

    // ---- choose plan ----
    int A_dc = 0, B_dc = 0, B_band = 0;
    long long A_gband = 0;
    if (ws_size > fixed) {
        size_t rem = ws_size - fixed;
        const int dcs[3] = {128, 64, 32};
        for (int k = 0; k < 3; ++k) {
            int dc = dcs[k];
            size_t Grow = (size_t)W2 * dc * 8;
            size_t Hrow = (size_t)WW * dc * 8;
            size_t Hfull = (size_t)(HH + 16) * Hrow;
            if (!A_dc && rem >= Hfull + 48*Grow) {
                A_dc = dc;
                A_gband = (long long)((rem - Hfull) / Grow);
                if (A_gband > HH + 16) A_gband = HH + 16;
            }
            if (!B_dc) {
                long long rows = (long long)(rem / (Grow + Hrow));
                if (rows - 16 >= 24) {
                    B_dc = dc;
                    long long b = rows - 16; if (b > HH) b = HH;
                    B_band = (int)b;
                }
            }
        }
    }

    if (!A_dc && !B_dc) {
        query_direct_kernel<<<(M+1)/2, 256, 0, stream>>>(
            qy, qx, qt, Tw, Xw, Yw, off, tss, xs, (float*)d_out,
            M, (long long)out_size, real_only);
        return;
    }

    qcnt_kernel<<<(M+255)/256, 256, 0, stream>>>(qy, qx, off, qcnt, M);

    // ---- query pixel-sort (reuses scan machinery; bs reused sequentially) ----
    hipMemsetAsync(qoff, 0, (size_t)HWPIX*4, stream);
    hist_kernel<<<(M+255)/256, 256, 0, stream>>>(qy, qx, qoff, M);
    scan1_kernel<<<NBLK, 256, 0, stream>>>(qoff, bs);
    scan2_kernel<<<1, 256, 0, stream>>>(bs);
    scan3_kernel<<<NBLK, 256, 0, stream>>>(qoff, bs);
    qsort_kernel<<<(M+255)/256, 256, 0, stream>>>(qy, qx, qoff, qidx, M);

    if (A_dc >= B_dc) {
        // ===== Plan A: full H per d-pass, banded G, single stage-2 dispatch =====
        const int DC = A_dc;
        size_t Hb = (size_t)(HH + 16) * WW * DC * 8;
        float2* H = (float2*)(ws + fixed);
        float2* G = (float2*)(ws + fixed + Hb);

#define PLANA(DCV)                                                                          \
        {                                                                                   \
            for (int gb0 = -RAD; gb0 < HH + RAD; gb0 += (int)A_gband) {                     \
                int rows = (int)((HH + RAD - gb0 < A_gband) ? (HH + RAD - gb0) : A_gband);  \
                long long bt = (long long)rows * W2 * DCV;                                  \
                build_kernel<DCV><<<(int)((bt+255)/256), 256, 0, stream>>>(                 \
                    off, tss, Tw, G, gb0 + RAD, rows, dlo);                                 \
                long long ct = (long long)rows * WW * DCV;                                  \
                convh_kernel<DCV><<<(int)((ct+255)/256), 256, 0, stream>>>(                 \
                    G, Xw, H + (size_t)(gb0 + RAD) * WW * DCV, rows, dlo);                  \
            }                                                                               \
            int qpb = 256 / DCV;                                                            \
            query_sep_kernel<DCV><<<(M+qpb-1)/qpb, 256, 0, stream>>>(                       \
                qidx, qy, qx, qt, Tw, Yw, H, qcnt, (float*)d_out,                           \
                M, 0, HH, -RAD, dlo, (long long)out_size, real_only);                       \
        }
        for (int dlo = 0; dlo < DD; dlo += DC) {
            switch (DC) {
                case 128: PLANA(128); break;
                case 64:  PLANA(64);  break;
                default:  PLANA(32);  break;
            }
        }
#undef PLANA
    } else {
        // ===== Plan B: banded G+H, early-exit stage-2 per band =====
        const int DC = B_dc;
        size_t Gb = (size_t)(B_band + 16) * W2 * DC * 8;
        float2* G = (float2*)(ws + fixed);
        float2* H = (float2*)(ws + fixed + Gb);

#define PLANB(DCV)                                                                          \
        {                                                                                   \
            long long bt = (long long)rows * W2 * DCV;                                      \
            build_kernel<DCV><<<(int)((bt+255)/256), 256, 0, stream>>>(                     \
                off, tss, Tw, G, r0, rows, dlo);                                            \
            long long ct = (long long)rows * WW * DCV;                                      \
            convh_kernel<DCV><<<(int)((ct+255)/256), 256, 0, stream>>>(                     \
                G, Xw, H, rows, dlo);                                                       \
            int qpb = 256 / DCV;                                                            \
            query_sep_kernel<DCV><<<(M+qpb-1)/qpb, 256, 0, stream>>>(                       \
                qidx, qy, qx, qt, Tw, Yw, H, qcnt, (float*)d_out,                           \
                M, r0, band, r0 - RAD, dlo, (long long)out_size, real_only);                \
        }
        for (int dlo = 0; dlo < DD; dlo += DC) {
            for (int r0 = 0; r0 < HH; r0 += B_band) {
                int band = (HH - r0 < B_band) ? (HH - r0) : B_band;
                int rows = band + 16;
                switch (DC) {
                    case 128: PLANB(128); break;
                    case 64:  PLANB(64);  break;
                    default:  PLANB(32);  break;
                }
            }
        }
#undef PLANB
    }
}

// Round 7
// 375.144 us; speedup vs baseline: 7.1726x; 2.4225x over previous
//
#include <hip/hip_runtime.h>
#include <math.h>

#define HH 480
#define WW 640
#define RAD 8
#define KK 17
#define DD 128
#define HWPIX (HH*WW)       // 307200
#define NBLK (HWPIX/256)    // 1200 exactly
#define TS 160              // x-tile width in rowsweep
#define XT 4                // tiles per row (XT*TS >= WW)

static inline size_t al256(size_t x){ return (x + 255) & ~(size_t)255; }

// ================= counting sort by pixel (validated v4-v6); reused for queries =================
__global__ void hist_kernel(const int* __restrict__ cy, const int* __restrict__ cx,
                            unsigned* __restrict__ off, int N) {
    int e = blockIdx.x*blockDim.x + threadIdx.x;
    if (e >= N) return;
    atomicAdd(&off[cy[e]*WW + cx[e]], 1u);
}

__global__ void scan1_kernel(unsigned* __restrict__ off, unsigned* __restrict__ bs) {
    __shared__ unsigned sh[256];
    int t = threadIdx.x, b = blockIdx.x;
    unsigned v = off[b*256 + t];
    sh[t] = v; __syncthreads();
    for (int st = 1; st < 256; st <<= 1) {
        unsigned a = (t >= st) ? sh[t-st] : 0u;
        __syncthreads();
        sh[t] += a;
        __syncthreads();
    }
    off[b*256 + t] = sh[t] - v;
    if (t == 255) bs[b] = sh[255];
}

__global__ void scan2_kernel(unsigned* __restrict__ bs) {
    __shared__ unsigned sh[256];
    __shared__ unsigned carry;
    int t = threadIdx.x;
    if (t == 0) carry = 0u;
    __syncthreads();
    for (int base = 0; base < NBLK; base += 256) {
        int i = base + t;
        unsigned v = (i < NBLK) ? bs[i] : 0u;
        sh[t] = v; __syncthreads();
        for (int st = 1; st < 256; st <<= 1) {
            unsigned a = (t >= st) ? sh[t-st] : 0u;
            __syncthreads();
            sh[t] += a;
            __syncthreads();
        }
        unsigned tot = sh[255];
        if (i < NBLK) bs[i] = (sh[t] - v) + carry;
        __syncthreads();
        if (t == 0) carry += tot;
        __syncthreads();
    }
}

__global__ void scan3_kernel(unsigned* __restrict__ off, const unsigned* __restrict__ bs) {
    int i = blockIdx.x*256 + threadIdx.x;
    off[i] += bs[blockIdx.x];
}

// leaves off[pix] = END of bucket; start = pix ? off[pix-1] : 0
__global__ void sort_kernel(const int* __restrict__ ey, const int* __restrict__ ex,
                            const float* __restrict__ t, unsigned* __restrict__ off,
                            float* __restrict__ tss, int* __restrict__ xs, int N) {
    int e = blockIdx.x*blockDim.x + threadIdx.x;
    if (e >= N) return;
    int pix = ey[e]*WW + ex[e];
    unsigned pos = atomicAdd(&off[pix], 1u);
    tss[pos] = t[e];
    xs[pos]  = ex[e];
}

__global__ void qsort_kernel(const int* __restrict__ qy, const int* __restrict__ qx,
                             unsigned* __restrict__ qoff, unsigned* __restrict__ qidx, int M) {
    int q = blockIdx.x*blockDim.x + threadIdx.x;
    if (q >= M) return;
    int pix = qy[q]*WW + qx[q];
    unsigned pos = atomicAdd(&qoff[pix], 1u);
    qidx[pos] = q;
}

// ---------- per-query window event count (telescoping row ranges; validated) ----------
__global__ void qcnt_kernel(const int* __restrict__ qy, const int* __restrict__ qx,
                            const unsigned* __restrict__ off, float* __restrict__ qcnt, int M) {
    int q = blockIdx.x*blockDim.x + threadIdx.x;
    if (q >= M) return;
    int cy = qy[q], cx = qx[q];
    int xlo = cx - RAD; if (xlo < 0) xlo = 0;
    int xhi = cx + RAD; if (xhi > WW-1) xhi = WW-1;
    unsigned s = 0;
    for (int i = 0; i < KK; ++i) {
        int yy = cy + i - RAD;
        if ((unsigned)yy >= HH) continue;
        int plo = yy*WW + xlo, phi = yy*WW + xhi;
        unsigned st = plo ? off[plo-1] : 0u;
        s += off[phi] - st;
    }
    qcnt[q] = (float)s;
}

// ================= fused build+convh: sliding-DFT row sweep =================
// H[hrow][x][dd] for hrow in [0, hrows), image row hy = rb0 + hrow (zero outside image).
// H[x] = sum_{j=0..16} e^{i*th*(j-8)} * G[imgcol x+j-8], th = X[d]/8
// Recurrence: H[x+1] = e^{-i th} * (H[x] - e^{-8i th} G[x-8] + e^{9i th} G[x+9])
__global__ __launch_bounds__(128) void rowsweep_kernel(
        const unsigned* __restrict__ off, const float* __restrict__ tss,
        const float* __restrict__ Tw, const float* __restrict__ Xw,
        float2* __restrict__ Hout, int rb0) {
    __shared__ float ringr[KK][DD];   // 17-deep G history, private per dd column
    __shared__ float ringi[KK][DD];
    int dd   = threadIdx.x;
    int hrow = blockIdx.y;
    int hy   = rb0 + hrow;
    int x0   = blockIdx.x * TS;
    int x1   = x0 + TS; if (x1 > WW) x1 = WW;
    float2* hp = Hout + (long long)hrow*WW*DD + dd;

    if ((unsigned)hy >= HH) {                       // zero-pad rows
        for (int x = x0; x < x1; ++x) hp[(long long)x*DD] = make_float2(0.f, 0.f);
        return;
    }

    float Td = Tw[dd];
    float th = Xw[dd] * 0.125f;
    float s, c;
    sincosf(th, &s, &c);
    const float er_ = c,  ei_ = s;    // e^{+i th}  (init weight step)
    const float ar  = c,  ai  = -s;   // e^{-i th}  (recurrence rotation)
    sincosf(8.f*th, &s, &c);
    const float w0r = c,  w0i = -s;   // e^{-8 i th}
    sincosf(9.f*th, &s, &c);
    const float w17r = c, w17i = s;   // e^{+9 i th}

    const int rowbase = hy*WW;
    const unsigned* offr = off + rowbase;

#define GAT(col, gr, gi)                                                    \
    {                                                                       \
        gr = 0.f; gi = 0.f;                                                 \
        if ((unsigned)(col) < WW) {                                         \
            int pix_ = rowbase + (col);                                     \
            unsigned st_ = pix_ ? off[pix_-1] : 0u;                         \
            unsigned en_ = offr[(col)];                                     \
            for (unsigned p_ = st_; p_ < en_; ++p_) {                       \
                float ss_, cc_;                                             \
                __sincosf(tss[p_]*Td, &ss_, &cc_);                          \
                gr += cc_; gi += ss_;                                       \
            }                                                               \
        }                                                                   \
    }

    // init: H[x0] direct 17-tap, fill ring with G[x0-8 .. x0+8]
    float hr = 0.f, hi = 0.f;
    float wr = w0r, wi = w0i;
    #pragma unroll
    for (int j = 0; j < KK; ++j) {
        float gr, gi; GAT(x0 + j - RAD, gr, gi);
        hr = fmaf(gr, wr, hr); hr = fmaf(-gi, wi, hr);
        hi = fmaf(gr, wi, hi); hi = fmaf(gi, wr, hi);
        ringr[j][dd] = gr; ringi[j][dd] = gi;
        float nr = wr*er_ - wi*ei_;
        wi       = wr*ei_ + wi*er_;
        wr       = nr;
    }
    hp[(long long)x0*DD] = make_float2(hr, hi);

    int ri = 0;
    for (int xn = x0 + 1; xn < x1; ++xn) {
        float gr, gi; GAT(xn + RAD, gr, gi);            // G[xn+8] (new)
        float gor = ringr[ri][dd], goi = ringi[ri][dd]; // G[xn-9] (old)
        ringr[ri][dd] = gr; ringi[ri][dd] = gi;
        ri = (ri + 1 == KK) ? 0 : ri + 1;
        float tr = hr - (gor*w0r - goi*w0i) + (gr*w17r - gi*w17i);
        float ti = hi - (gor*w0i + goi*w0r) + (gr*w17i + gi*w17r);
        hr = tr*ar - ti*ai;
        hi = tr*ai + ti*ar;
        hp[(long long)xn*DD] = make_float2(hr, hi);
    }
#undef GAT
}

// ================= stage 2: 17-tap vertical gather on H, sorted queries (validated v6) ==========
__global__ __launch_bounds__(256) void query_sep_kernel(
        const unsigned* __restrict__ qidx, const int* __restrict__ qy,
        const int* __restrict__ qx, const float* __restrict__ qt,
        const float* __restrict__ Tw, const float* __restrict__ Yw,
        const float2* __restrict__ H, const float* __restrict__ qcnt,
        float* __restrict__ out, int M, int r0, int band, int rb0,
        long long out_n, int real_only) {
    int lt = threadIdx.x;
    int p  = blockIdx.x*2 + (lt >> 7);
    int dd = lt & (DD-1);
    if (p >= M) return;
    int q = (int)qidx[p];
    int cy = qy[q];
    if (cy < r0 || cy >= r0 + band) return;
    int cx = qx[q];

    float wyr, wyi, cst, sst;
    {
        float s, c, Yd = Yw[dd];
        sincosf(-Yd, &s, &c);        wyr = c; wyi = s;
        sincosf(Yd * 0.125f, &sst, &cst);
    }

    const float2* hp = H + ((long long)(cy - RAD - rb0)*WW + cx)*DD + dd;
    float er = 0.f, ei = 0.f;
    #pragma unroll
    for (int i = 0; i < KK; ++i) {
        float2 f = hp[(long long)i*WW*DD];
        er = fmaf(f.x, wyr, er); er = fmaf(-f.y, wyi, er);
        ei = fmaf(f.x, wyi, ei); ei = fmaf(f.y, wyr, ei);
        float nr = wyr*cst - wyi*sst;
        wyi      = wyr*sst + wyi*cst;
        wyr      = nr;
    }

    float s, c;
    sincosf(qt[q] * Tw[dd], &s, &c);         // recen = exp(-i qt T_d)
    float inv = 1.0f / fmaxf(qcnt[q], 1.0f);
    float outr = (er*c + ei*s) * inv;
    float outi = (ei*c - er*s) * inv;
    long long base = (long long)q*DD + dd;
    if (real_only) { if (base < out_n) out[base] = outr; }
    else if (2*base + 1 < out_n) { out[2*base] = outr; out[2*base+1] = outi; }
}

// ================= fallback: event-direct query (validated v4, 2.69 ms) =================
__global__ __launch_bounds__(256) void query_direct_kernel(
        const int* __restrict__ qy, const int* __restrict__ qx,
        const float* __restrict__ qt, const float* __restrict__ Tw,
        const float* __restrict__ Xw, const float* __restrict__ Yw,
        const unsigned* __restrict__ off, const float* __restrict__ tss,
        const int* __restrict__ xs, float* __restrict__ out,
        int M, long long out_n, int real_only) {
    __shared__ float2 swx[KK*DD];
    __shared__ float2 swy[KK*DD];
    int lt = threadIdx.x;
    for (int idx = lt; idx < KK*DD; idx += 256) {
        int j = idx / DD, dd = idx & (DD-1);
        float s, c;
        sincosf((float)(j - RAD) * 0.125f * Xw[dd], &s, &c);
        swx[idx] = make_float2(c, s);
        sincosf((float)(j - RAD) * 0.125f * Yw[dd], &s, &c);
        swy[idx] = make_float2(c, s);
    }
    __syncthreads();

    int q = blockIdx.x*2 + (lt >> 7);
    int d = lt & (DD-1);
    if (q >= M) return;

    int cy = qy[q], cx = qx[q];
    float Td = Tw[d];
    int xlo = cx - RAD; if (xlo < 0) xlo = 0;
    int xhi = cx + RAD; if (xhi > WW-1) xhi = WW-1;

    float accr = 0.f, acci = 0.f;
    unsigned cnt = 0;
    for (int i = 0; i < KK; ++i) {
        int yy = cy + i - RAD;
        if ((unsigned)yy >= HH) continue;
        int plo = yy*WW + xlo, phi = yy*WW + xhi;
        unsigned st = plo ? off[plo-1] : 0u;
        unsigned en = off[phi];
        cnt += en - st;
        float rr = 0.f, ri = 0.f;
        for (unsigned p = st; p < en; ++p) {
            float te = tss[p];
            int   xe = xs[p];
            float2 wx = swx[(xe - cx + RAD)*DD + d];
            float s, c;
            __sincosf(te * Td, &s, &c);
            rr = fmaf(c, wx.x, rr); rr = fmaf(-s, wx.y, rr);
            ri = fmaf(c, wx.y, ri); ri = fmaf(s, wx.x, ri);
        }
        float2 wy = swy[i*DD + d];
        accr = fmaf(rr, wy.x, accr); accr = fmaf(-ri, wy.y, accr);
        acci = fmaf(rr, wy.y, acci); acci = fmaf(ri, wy.x, acci);
    }

    float s, c;
    sincosf(qt[q] * Td, &s, &c);
    float inv = 1.0f / fmaxf((float)cnt, 1.0f);
    float outr = (accr*c + acci*s) * inv;
    float outi = (acci*c - accr*s) * inv;
    long long base = (long long)q*DD + d;
    if (real_only) { if (base < out_n) out[base] = outr; }
    else if (2*base + 1 < out_n) { out[2*base] = outr; out[2*base+1] = outi; }
}

extern "C" void kernel_launch(void* const* d_in, const int* in_sizes, int n_in,
                              void* d_out, int out_size, void* d_ws, size_t ws_size,
                              hipStream_t stream) {
    const float* t  = (const float*)d_in[0];
    const int*   ey = (const int*)d_in[1];
    const int*   ex = (const int*)d_in[2];
    const int*   qy = (const int*)d_in[3];
    const int*   qx = (const int*)d_in[4];
    const float* qt = (const float*)d_in[5];
    const float* Tw = (const float*)d_in[6];
    const float* Xw = (const float*)d_in[7];
    const float* Yw = (const float*)d_in[8];

    int N = in_sizes[0];
    int M = in_sizes[3];

    // ws: [off | bs | tss | xs | qoff | qidx | qcnt | H band]
    size_t off_b  = al256((size_t)HWPIX*4);
    size_t bs_b   = al256((size_t)NBLK*4);
    size_t tss_b  = al256((size_t)N*4);
    size_t xs_b   = al256((size_t)N*4);
    size_t qoff_b = al256((size_t)HWPIX*4);
    size_t qidx_b = al256((size_t)M*4);
    size_t qc_b   = al256((size_t)M*4);
    size_t fixed  = off_b + bs_b + tss_b + xs_b + qoff_b + qidx_b + qc_b;  // ~8.5 MB
    size_t need_min = off_b + bs_b + tss_b + xs_b;                          // ~5.3 MB

    if (ws_size < need_min || d_ws == nullptr) {
        hipMemsetAsync(d_out, 0, (size_t)out_size*4, stream);   // safe diagnostic
        return;
    }

    char*     ws   = (char*)d_ws;
    unsigned* off  = (unsigned*)ws;
    unsigned* bs   = (unsigned*)(ws + off_b);
    float*    tss  = (float*)(ws + off_b + bs_b);
    int*      xs   = (int*)(ws + off_b + bs_b + tss_b);
    unsigned* qoff = (unsigned*)(ws + off_b + bs_b + tss_b + xs_b);
    unsigned* qidx = (unsigned*)(ws + off_b + bs_b + tss_b + xs_b + qoff_b);
    float*    qcnt = (float*)(ws + off_b + bs_b + tss_b + xs_b + qoff_b + qidx_b);
    float2*   H    = (float2*)(ws + fixed);

    long long full = (long long)M * DD;
    int real_only = (out_size < 2*full) ? 1 : 0;

    // ---- event sort (validated) ----
    hipMemsetAsync(off, 0, (size_t)HWPIX*4, stream);
    hist_kernel<<<(N+255)/256, 256, 0, stream>>>(ey, ex, off, N);
    scan1_kernel<<<NBLK, 256, 0, stream>>>(off, bs);
    scan2_kernel<<<1, 256, 0, stream>>>(bs);
    scan3_kernel<<<NBLK, 256, 0, stream>>>(off, bs);
    sort_kernel<<<(N+255)/256, 256, 0, stream>>>(ey, ex, t, off, tss, xs, N);

    // ---- band sizing: H rows fit in remaining ws ----
    long long band_sz = 0;
    if (ws_size > fixed) {
        long long hrows_fit = (long long)((ws_size - fixed) / ((size_t)WW*DD*8));
        band_sz = hrows_fit - 16;
        if (band_sz > HH) band_sz = HH;
    }

    if (band_sz < 32) {
        query_direct_kernel<<<(M+1)/2, 256, 0, stream>>>(
            qy, qx, qt, Tw, Xw, Yw, off, tss, xs, (float*)d_out,
            M, (long long)out_size, real_only);
        return;
    }

    qcnt_kernel<<<(M+255)/256, 256, 0, stream>>>(qy, qx, off, qcnt, M);

    // ---- query pixel-sort for stage-2 locality (validated v6) ----
    hipMemsetAsync(qoff, 0, (size_t)HWPIX*4, stream);
    hist_kernel<<<(M+255)/256, 256, 0, stream>>>(qy, qx, qoff, M);
    scan1_kernel<<<NBLK, 256, 0, stream>>>(qoff, bs);
    scan2_kernel<<<1, 256, 0, stream>>>(bs);
    scan3_kernel<<<NBLK, 256, 0, stream>>>(qoff, bs);
    qsort_kernel<<<(M+255)/256, 256, 0, stream>>>(qy, qx, qoff, qidx, M);

    // ---- banded sweep + gather ----
    for (int r0 = 0; r0 < HH; r0 += (int)band_sz) {
        int band  = (HH - r0 < band_sz) ? (HH - r0) : (int)band_sz;
        int hrows = band + 16;
        dim3 g(XT, hrows);
        rowsweep_kernel<<<g, 128, 0, stream>>>(off, tss, Tw, Xw, H, r0 - RAD);
        query_sep_kernel<<<(M+1)/2, 256, 0, stream>>>(
            qidx, qy, qx, qt, Tw, Yw, H, qcnt, (float*)d_out,
            M, r0, band, r0 - RAD, (long long)out_size, real_only);
    }
}

// Round 8
// 252.640 us; speedup vs baseline: 10.6505x; 1.4849x over previous
//
#include <hip/hip_runtime.h>
#include <hip/hip_fp16.h>
#include <math.h>

#define HH 480
#define WW 640
#define RAD 8
#define KK 17
#define DD 128
#define HWPIX (HH*WW)       // 307200
#define NBLK (HWPIX/256)    // 1200 exactly
#define TS 160              // x-tile width in rowsweep
#define XT 4                // tiles per row (XT*TS >= WW)

static inline size_t al256(size_t x){ return (x + 255) & ~(size_t)255; }

// ================= counting sort by pixel (validated v4-v7); reused for queries =================
__global__ void hist_kernel(const int* __restrict__ cy, const int* __restrict__ cx,
                            unsigned* __restrict__ off, int N) {
    int e = blockIdx.x*blockDim.x + threadIdx.x;
    if (e >= N) return;
    atomicAdd(&off[cy[e]*WW + cx[e]], 1u);
}

__global__ void scan1_kernel(unsigned* __restrict__ off, unsigned* __restrict__ bs) {
    __shared__ unsigned sh[256];
    int t = threadIdx.x, b = blockIdx.x;
    unsigned v = off[b*256 + t];
    sh[t] = v; __syncthreads();
    for (int st = 1; st < 256; st <<= 1) {
        unsigned a = (t >= st) ? sh[t-st] : 0u;
        __syncthreads();
        sh[t] += a;
        __syncthreads();
    }
    off[b*256 + t] = sh[t] - v;
    if (t == 255) bs[b] = sh[255];
}

__global__ void scan2_kernel(unsigned* __restrict__ bs) {
    __shared__ unsigned sh[256];
    __shared__ unsigned carry;
    int t = threadIdx.x;
    if (t == 0) carry = 0u;
    __syncthreads();
    for (int base = 0; base < NBLK; base += 256) {
        int i = base + t;
        unsigned v = (i < NBLK) ? bs[i] : 0u;
        sh[t] = v; __syncthreads();
        for (int st = 1; st < 256; st <<= 1) {
            unsigned a = (t >= st) ? sh[t-st] : 0u;
            __syncthreads();
            sh[t] += a;
            __syncthreads();
        }
        unsigned tot = sh[255];
        if (i < NBLK) bs[i] = (sh[t] - v) + carry;
        __syncthreads();
        if (t == 0) carry += tot;
        __syncthreads();
    }
}

__global__ void scan3_kernel(unsigned* __restrict__ off, const unsigned* __restrict__ bs) {
    int i = blockIdx.x*256 + threadIdx.x;
    off[i] += bs[blockIdx.x];
}

// leaves off[pix] = END of bucket; start = pix ? off[pix-1] : 0
__global__ void sort_kernel(const int* __restrict__ ey, const int* __restrict__ ex,
                            const float* __restrict__ t, unsigned* __restrict__ off,
                            float* __restrict__ tss, int* __restrict__ xs, int N) {
    int e = blockIdx.x*blockDim.x + threadIdx.x;
    if (e >= N) return;
    int pix = ey[e]*WW + ex[e];
    unsigned pos = atomicAdd(&off[pix], 1u);
    tss[pos] = t[e];
    xs[pos]  = ex[e];
}

__global__ void qsort_kernel(const int* __restrict__ qy, const int* __restrict__ qx,
                             unsigned* __restrict__ qoff, unsigned* __restrict__ qidx, int M) {
    int q = blockIdx.x*blockDim.x + threadIdx.x;
    if (q >= M) return;
    int pix = qy[q]*WW + qx[q];
    unsigned pos = atomicAdd(&qoff[pix], 1u);
    qidx[pos] = q;
}

// ---------- per-query window event count (telescoping row ranges; validated) ----------
__global__ void qcnt_kernel(const int* __restrict__ qy, const int* __restrict__ qx,
                            const unsigned* __restrict__ off, float* __restrict__ qcnt, int M) {
    int q = blockIdx.x*blockDim.x + threadIdx.x;
    if (q >= M) return;
    int cy = qy[q], cx = qx[q];
    int xlo = cx - RAD; if (xlo < 0) xlo = 0;
    int xhi = cx + RAD; if (xhi > WW-1) xhi = WW-1;
    unsigned s = 0;
    for (int i = 0; i < KK; ++i) {
        int yy = cy + i - RAD;
        if ((unsigned)yy >= HH) continue;
        int plo = yy*WW + xlo, phi = yy*WW + xhi;
        unsigned st = plo ? off[plo-1] : 0u;
        s += off[phi] - st;
    }
    qcnt[q] = (float)s;
}

// ================= fused build+convh: sliding-DFT row sweep, half2 H output =================
// H[hrow][x][dd] (packed half2) for image row hy = rb0 + hrow (zero outside image).
// Recurrence (fp32 internal): H[x+1] = e^{-i th} (H[x] - e^{-8i th} G[x-8] + e^{9i th} G[x+9])
__global__ __launch_bounds__(128) void rowsweep_kernel(
        const unsigned* __restrict__ off, const float* __restrict__ tss,
        const float* __restrict__ Tw, const float* __restrict__ Xw,
        __half2* __restrict__ Hout, int rb0) {
    __shared__ float ringr[KK][DD];   // 17-deep G history, private per dd column
    __shared__ float ringi[KK][DD];
    int dd   = threadIdx.x;
    int hrow = blockIdx.y;
    int hy   = rb0 + hrow;
    int x0   = blockIdx.x * TS;
    int x1   = x0 + TS; if (x1 > WW) x1 = WW;
    __half2* hp = Hout + (long long)hrow*WW*DD + dd;

    if ((unsigned)hy >= HH) {                       // zero-pad rows
        __half2 z = __floats2half2_rn(0.f, 0.f);
        for (int x = x0; x < x1; ++x) hp[(long long)x*DD] = z;
        return;
    }

    float Td = Tw[dd];
    float th = Xw[dd] * 0.125f;
    float s, c;
    sincosf(th, &s, &c);
    const float er_ = c,  ei_ = s;    // e^{+i th}  (init weight step)
    const float ar  = c,  ai  = -s;   // e^{-i th}  (recurrence rotation)
    sincosf(8.f*th, &s, &c);
    const float w0r = c,  w0i = -s;   // e^{-8 i th}
    sincosf(9.f*th, &s, &c);
    const float w17r = c, w17i = s;   // e^{+9 i th}

    const int rowbase = hy*WW;
    const unsigned* offr = off + rowbase;

#define GAT(col, gr, gi)                                                    \
    {                                                                       \
        gr = 0.f; gi = 0.f;                                                 \
        if ((unsigned)(col) < WW) {                                         \
            int pix_ = rowbase + (col);                                     \
            unsigned st_ = pix_ ? off[pix_-1] : 0u;                         \
            unsigned en_ = offr[(col)];                                     \
            for (unsigned p_ = st_; p_ < en_; ++p_) {                       \
                float ss_, cc_;                                             \
                __sincosf(tss[p_]*Td, &ss_, &cc_);                          \
                gr += cc_; gi += ss_;                                       \
            }                                                               \
        }                                                                   \
    }

    // init: H[x0] direct 17-tap, fill ring with G[x0-8 .. x0+8]
    float hr = 0.f, hi = 0.f;
    float wr = w0r, wi = w0i;
    #pragma unroll
    for (int j = 0; j < KK; ++j) {
        float gr, gi; GAT(x0 + j - RAD, gr, gi);
        hr = fmaf(gr, wr, hr); hr = fmaf(-gi, wi, hr);
        hi = fmaf(gr, wi, hi); hi = fmaf(gi, wr, hi);
        ringr[j][dd] = gr; ringi[j][dd] = gi;
        float nr = wr*er_ - wi*ei_;
        wi       = wr*ei_ + wi*er_;
        wr       = nr;
    }
    hp[(long long)x0*DD] = __floats2half2_rn(hr, hi);

    int ri = 0;
    for (int xn = x0 + 1; xn < x1; ++xn) {
        float gr, gi; GAT(xn + RAD, gr, gi);            // G[xn+8] (new)
        float gor = ringr[ri][dd], goi = ringi[ri][dd]; // G[xn-9] (old)
        ringr[ri][dd] = gr; ringi[ri][dd] = gi;
        ri = (ri + 1 == KK) ? 0 : ri + 1;
        float tr = hr - (gor*w0r - goi*w0i) + (gr*w17r - gi*w17i);
        float ti = hi - (gor*w0i + goi*w0r) + (gr*w17i + gi*w17r);
        hr = tr*ar - ti*ai;
        hi = tr*ai + ti*ar;
        hp[(long long)xn*DD] = __floats2half2_rn(hr, hi);
    }
#undef GAT
}

// ================= stage 2: 17-tap vertical gather on half2 H, 2 dims/lane =================
// wave64 handles one query: lane l covers d0=2l, d1=2l+1 (uint2 = two half2 = 8B loads)
__global__ __launch_bounds__(256) void query_sep_kernel(
        const unsigned* __restrict__ qidx, const int* __restrict__ qy,
        const int* __restrict__ qx, const float* __restrict__ qt,
        const float* __restrict__ Tw, const float* __restrict__ Yw,
        const unsigned* __restrict__ H, const float* __restrict__ qcnt,
        float* __restrict__ out, int M, int r0, int band, int rb0,
        long long out_n, int real_only) {
    int lt   = threadIdx.x;
    int p    = blockIdx.x*4 + (lt >> 6);
    int lane = lt & 63;
    if (p >= M) return;
    int q = (int)qidx[p];
    int cy = qy[q];
    if (cy < r0 || cy >= r0 + band) return;
    int cx = qx[q];
    int d0 = lane*2, d1 = d0 + 1;

    float wyr0, wyi0, cst0, sst0, wyr1, wyi1, cst1, sst1;
    {
        float s, c;
        float Y0 = Yw[d0], Y1 = Yw[d1];
        sincosf(-Y0, &s, &c);        wyr0 = c; wyi0 = s;
        sincosf(Y0*0.125f, &sst0, &cst0);
        sincosf(-Y1, &s, &c);        wyr1 = c; wyi1 = s;
        sincosf(Y1*0.125f, &sst1, &cst1);
    }

    const unsigned* hp = H + ((long long)(cy - RAD - rb0)*WW + cx)*DD + d0;
    float er0 = 0.f, ei0 = 0.f, er1 = 0.f, ei1 = 0.f;
    #pragma unroll
    for (int i = 0; i < KK; ++i) {
        uint2 v = *(const uint2*)(hp + (long long)i*WW*DD);
        float2 f0 = __half22float2(*(const __half2*)&v.x);
        float2 f1 = __half22float2(*(const __half2*)&v.y);
        er0 = fmaf(f0.x, wyr0, er0); er0 = fmaf(-f0.y, wyi0, er0);
        ei0 = fmaf(f0.x, wyi0, ei0); ei0 = fmaf(f0.y, wyr0, ei0);
        er1 = fmaf(f1.x, wyr1, er1); er1 = fmaf(-f1.y, wyi1, er1);
        ei1 = fmaf(f1.x, wyi1, ei1); ei1 = fmaf(f1.y, wyr1, ei1);
        float nr;
        nr = wyr0*cst0 - wyi0*sst0; wyi0 = wyr0*sst0 + wyi0*cst0; wyr0 = nr;
        nr = wyr1*cst1 - wyi1*sst1; wyi1 = wyr1*sst1 + wyi1*cst1; wyr1 = nr;
    }

    float inv = 1.0f / fmaxf(qcnt[q], 1.0f);
    float s, c, qtv = qt[q];
    sincosf(qtv * Tw[d0], &s, &c);
    float outr0 = (er0*c + ei0*s) * inv, outi0 = (ei0*c - er0*s) * inv;
    sincosf(qtv * Tw[d1], &s, &c);
    float outr1 = (er1*c + ei1*s) * inv, outi1 = (ei1*c - er1*s) * inv;

    long long base = (long long)q*DD + d0;
    if (real_only) {
        if (base + 1 < out_n) *(float2*)(out + base) = make_float2(outr0, outr1);
        else if (base < out_n) out[base] = outr0;
    } else if (2*base + 3 < out_n) {
        *(float4*)(out + 2*base) = make_float4(outr0, outi0, outr1, outi1);
    }
}

// ================= fallback: event-direct query (validated v4, 2.69 ms) =================
__global__ __launch_bounds__(256) void query_direct_kernel(
        const int* __restrict__ qy, const int* __restrict__ qx,
        const float* __restrict__ qt, const float* __restrict__ Tw,
        const float* __restrict__ Xw, const float* __restrict__ Yw,
        const unsigned* __restrict__ off, const float* __restrict__ tss,
        const int* __restrict__ xs, float* __restrict__ out,
        int M, long long out_n, int real_only) {
    __shared__ float2 swx[KK*DD];
    __shared__ float2 swy[KK*DD];
    int lt = threadIdx.x;
    for (int idx = lt; idx < KK*DD; idx += 256) {
        int j = idx / DD, dd = idx & (DD-1);
        float s, c;
        sincosf((float)(j - RAD) * 0.125f * Xw[dd], &s, &c);
        swx[idx] = make_float2(c, s);
        sincosf((float)(j - RAD) * 0.125f * Yw[dd], &s, &c);
        swy[idx] = make_float2(c, s);
    }
    __syncthreads();

    int q = blockIdx.x*2 + (lt >> 7);
    int d = lt & (DD-1);
    if (q >= M) return;

    int cy = qy[q], cx = qx[q];
    float Td = Tw[d];
    int xlo = cx - RAD; if (xlo < 0) xlo = 0;
    int xhi = cx + RAD; if (xhi > WW-1) xhi = WW-1;

    float accr = 0.f, acci = 0.f;
    unsigned cnt = 0;
    for (int i = 0; i < KK; ++i) {
        int yy = cy + i - RAD;
        if ((unsigned)yy >= HH) continue;
        int plo = yy*WW + xlo, phi = yy*WW + xhi;
        unsigned st = plo ? off[plo-1] : 0u;
        unsigned en = off[phi];
        cnt += en - st;
        float rr = 0.f, ri = 0.f;
        for (unsigned p = st; p < en; ++p) {
            float te = tss[p];
            int   xe = xs[p];
            float2 wx = swx[(xe - cx + RAD)*DD + d];
            float s, c;
            __sincosf(te * Td, &s, &c);
            rr = fmaf(c, wx.x, rr); rr = fmaf(-s, wx.y, rr);
            ri = fmaf(c, wx.y, ri); ri = fmaf(s, wx.x, ri);
        }
        float2 wy = swy[i*DD + d];
        accr = fmaf(rr, wy.x, accr); accr = fmaf(-ri, wy.y, accr);
        acci = fmaf(rr, wy.y, acci); acci = fmaf(ri, wy.x, acci);
    }

    float s, c;
    sincosf(qt[q] * Td, &s, &c);
    float inv = 1.0f / fmaxf((float)cnt, 1.0f);
    float outr = (accr*c + acci*s) * inv;
    float outi = (acci*c - accr*s) * inv;
    long long base = (long long)q*DD + d;
    if (real_only) { if (base < out_n) out[base] = outr; }
    else if (2*base + 1 < out_n) { out[2*base] = outr; out[2*base+1] = outi; }
}

extern "C" void kernel_launch(void* const* d_in, const int* in_sizes, int n_in,
                              void* d_out, int out_size, void* d_ws, size_t ws_size,
                              hipStream_t stream) {
    const float* t  = (const float*)d_in[0];
    const int*   ey = (const int*)d_in[1];
    const int*   ex = (const int*)d_in[2];
    const int*   qy = (const int*)d_in[3];
    const int*   qx = (const int*)d_in[4];
    const float* qt = (const float*)d_in[5];
    const float* Tw = (const float*)d_in[6];
    const float* Xw = (const float*)d_in[7];
    const float* Yw = (const float*)d_in[8];

    int N = in_sizes[0];
    int M = in_sizes[3];

    // ws: [off | qoff | bs | tss | xs | qidx | qcnt | H band (half2)]
    size_t off_b  = al256((size_t)HWPIX*4);
    size_t qoff_b = al256((size_t)HWPIX*4);
    size_t bs_b   = al256((size_t)NBLK*4);
    size_t tss_b  = al256((size_t)N*4);
    size_t xs_b   = al256((size_t)N*4);
    size_t qidx_b = al256((size_t)M*4);
    size_t qc_b   = al256((size_t)M*4);
    size_t fixed  = off_b + qoff_b + bs_b + tss_b + xs_b + qidx_b + qc_b;  // ~8.5 MB
    size_t need_min = off_b + qoff_b + bs_b + tss_b + xs_b;

    if (ws_size < need_min || d_ws == nullptr) {
        hipMemsetAsync(d_out, 0, (size_t)out_size*4, stream);   // safe diagnostic
        return;
    }

    char*     ws   = (char*)d_ws;
    unsigned* off  = (unsigned*)ws;
    unsigned* qoff = (unsigned*)(ws + off_b);
    unsigned* bs   = (unsigned*)(ws + off_b + qoff_b);
    float*    tss  = (float*)(ws + off_b + qoff_b + bs_b);
    int*      xs   = (int*)(ws + off_b + qoff_b + bs_b + tss_b);
    unsigned* qidx = (unsigned*)(ws + off_b + qoff_b + bs_b + tss_b + xs_b);
    float*    qcnt = (float*)(ws + off_b + qoff_b + bs_b + tss_b + xs_b + qidx_b);
    __half2*  H    = (__half2*)(ws + fixed);

    long long full = (long long)M * DD;
    int real_only = (out_size < 2*full) ? 1 : 0;

    // ---- event sort (validated); one memset covers off+qoff (adjacent) ----
    hipMemsetAsync(off, 0, off_b + (size_t)HWPIX*4, stream);
    hist_kernel<<<(N+255)/256, 256, 0, stream>>>(ey, ex, off, N);
    scan1_kernel<<<NBLK, 256, 0, stream>>>(off, bs);
    scan2_kernel<<<1, 256, 0, stream>>>(bs);
    scan3_kernel<<<NBLK, 256, 0, stream>>>(off, bs);
    sort_kernel<<<(N+255)/256, 256, 0, stream>>>(ey, ex, t, off, tss, xs, N);

    // ---- band sizing: H rows (half2 elems, 4B) fit in remaining ws ----
    long long band_sz = 0;
    if (ws_size > fixed) {
        long long hrows_fit = (long long)((ws_size - fixed) / ((size_t)WW*DD*4));
        band_sz = hrows_fit - 16;
        if (band_sz > HH) band_sz = HH;
    }

    if (band_sz < 32) {
        query_direct_kernel<<<(M+1)/2, 256, 0, stream>>>(
            qy, qx, qt, Tw, Xw, Yw, off, tss, xs, (float*)d_out,
            M, (long long)out_size, real_only);
        return;
    }

    qcnt_kernel<<<(M+255)/256, 256, 0, stream>>>(qy, qx, off, qcnt, M);

    // ---- query pixel-sort for stage-2 locality (validated v6) ----
    hist_kernel<<<(M+255)/256, 256, 0, stream>>>(qy, qx, qoff, M);
    scan1_kernel<<<NBLK, 256, 0, stream>>>(qoff, bs);
    scan2_kernel<<<1, 256, 0, stream>>>(bs);
    scan3_kernel<<<NBLK, 256, 0, stream>>>(qoff, bs);
    qsort_kernel<<<(M+255)/256, 256, 0, stream>>>(qy, qx, qoff, qidx, M);

    // ---- banded sweep + gather ----
    for (int r0 = 0; r0 < HH; r0 += (int)band_sz) {
        int band  = (HH - r0 < band_sz) ? (HH - r0) : (int)band_sz;
        int hrows = band + 16;
        dim3 g(XT, hrows);
        rowsweep_kernel<<<g, 128, 0, stream>>>(off, tss, Tw, Xw, H, r0 - RAD);
        query_sep_kernel<<<(M+3)/4, 256, 0, stream>>>(
            qidx, qy, qx, qt, Tw, Yw, (const unsigned*)H, qcnt, (float*)d_out,
            M, r0, band, r0 - RAD, (long long)out_size, real_only);
    }
}